// Round 9
// baseline (1407.598 us; speedup 1.0000x reference)
//
#include <hip/hip_runtime.h>
#include <stdint.h>

typedef unsigned long long u64;

#define NVAR 8192
#define NCLS 32768
#define CSEG 16
#define GSEG 4           // gather segments (128 chunks each)
#define LCAP 1152        // per-warp gather list capacity

__device__ __forceinline__ float lane_bc(float v, int l) { return __shfl(v, l); }

__device__ __forceinline__ u64 readfl64(u64 x) {
  unsigned lo = __builtin_amdgcn_readfirstlane((unsigned)x);
  unsigned hi = __builtin_amdgcn_readfirstlane((unsigned)(x >> 32));
  return ((u64)hi << 32) | (u64)lo;
}

__device__ __forceinline__ u64 shflx64(u64 x, int m) {
  unsigned lo = (unsigned)__shfl_xor((int)(unsigned)x, m, 64);
  unsigned hi = (unsigned)__shfl_xor((int)(unsigned)(x >> 32), m, 64);
  return ((u64)hi << 32) | (u64)lo;
}

#define LGKM0() do { asm volatile("s_waitcnt lgkmcnt(0)" ::: "memory"); \
                     __builtin_amdgcn_sched_barrier(0); } while (0)
#define SBAR()  do { __builtin_amdgcn_s_barrier(); \
                     __builtin_amdgcn_sched_barrier(0); } while (0)

// ---------------- kernel 1: vars_fwd = v @ fb0^T  [NVAR,64] ----------------
__global__ __launch_bounds__(256) void k_varsfwd(const float* __restrict__ v,
                                                 const float* __restrict__ fb0,
                                                 float* __restrict__ out) {
  __shared__ float fbt[64 * 64];   // fbt[k][d] = fb0[d][k]
  __shared__ float vrow[4][64];
  int t = threadIdx.x;
#pragma unroll
  for (int i = 0; i < 16; ++i) {
    int idx = i * 256 + t;                       // idx = d*64+k
    fbt[(idx & 63) * 64 + (idx >> 6)] = fb0[idx];
  }
  __syncthreads();
  int w = t >> 6, lane = t & 63;
  for (int rr = 0; rr < 16; rr += 4) {
    int row = blockIdx.x * 16 + rr + w;
    vrow[w][lane] = v[row * 64 + lane];
    __syncthreads();
    double a = 0.0;
#pragma unroll
    for (int k = 0; k < 64; ++k)
      a = fma((double)vrow[w][k], (double)fbt[k * 64 + lane], a);
    out[row * 64 + lane] = (float)a;
    __syncthreads();
  }
}

// ======================= FAST PATH =======================
// pass 1 v5: v3 phase structure + raw (non-draining) barriers + one-group
// pos/neg VGPR prefetch + nontemporal vbs stores. Per group:
//  ph1 ballots(P regs) -> BAR1 -> ph2 {ds_write h0; issue stage-h1 + P(g+1);
//  transpose + nt-store} -> BAR2 -> ph3 gather h0 -> BAR3 ->
//  ph4 ds_write h1 -> BAR4 -> ph5 {issue stage-h0(g+1); gather h1}.
__global__ __launch_bounds__(512, 7) void k_pass1v5(
    const float* __restrict__ pos, const float* __restrict__ neg,
    const float* __restrict__ vfwd, const float* __restrict__ fb1,
    const float* __restrict__ cbias, float* __restrict__ dmat,
    u64* __restrict__ vbs) {
  __shared__ __align__(16) float sbuf[128 * 64];   // 32KB, time-shared halves
  __shared__ __align__(16) u64 lms[2][32][4][2];   // [par][cl][j][{mask,sign}]
  int t = threadIdx.x;
  int w = __builtin_amdgcn_readfirstlane(t >> 6);  // warp 0..7 (SGPR)
  int lane = t & 63;
  int bx = blockIdx.x;             // 0..1023
  int c0 = bx * 32;                // first clause
  int cb = bx >> 1;                // 64-clause chunk
  int h = bx & 1;                  // which u64 slot (32-clause half)
  double acc[4];
#pragma unroll
  for (int i = 0; i < 4; ++i) acc[i] = 0.0;

  const float4* P4 = (const float4*)pos;
  const float4* Q4 = (const float4*)neg;
  const float4* V4 = (const float4*)vfwd;
  const size_t rbase = (size_t)(c0 + w * 4) * 2048 + lane;  // float4 units

  // prologue: issue P(0) (8 loads) then stage-h0(0) (4 loads)
  float4 p0 = P4[rbase], q0 = Q4[rbase];
  float4 p1 = P4[rbase + 2048], q1 = Q4[rbase + 2048];
  float4 p2 = P4[rbase + 4096], q2 = Q4[rbase + 4096];
  float4 p3 = P4[rbase + 6144], q3 = Q4[rbase + 6144];
  float4 st0, st1, st2, st3;
  {
    const float4* src = V4;                        // group 0, half 0
    st0 = src[t]; st1 = src[t + 512]; st2 = src[t + 1024]; st3 = src[t + 1536];
  }

  for (int g = 0; g < 32; ++g) {
    int par = g & 1;
    int gn = (g < 31) ? g + 1 : 31;
    // ---- ph1: ballots from prefetched p/q -> lms[par] ----
    auto ball = [&](float4 P, float4 Q, int cl) {
      float sc[4] = {P.x - Q.x, P.y - Q.y, P.z - Q.z, P.w - Q.w};
#pragma unroll
      for (int j = 0; j < 4; ++j) {
        u64 m = __ballot(sc[j] != 0.f);
        u64 sg = __ballot(sc[j] < 0.f);
        if (lane == j) { lms[par][cl][j][0] = m; lms[par][cl][j][1] = sg; }
      }
    };
    ball(p0, q0, w * 4 + 0);
    ball(p1, q1, w * 4 + 1);
    ball(p2, q2, w * 4 + 2);
    ball(p3, q3, w * 4 + 3);
    LGKM0();
    SBAR();                                        // BAR1: masks ready

    // ---- ph2: write sbuf h0; refill st (h1) and p/q (g+1); transpose ----
    {
      float4* dst = (float4*)sbuf;
      dst[t] = st0; dst[t + 512] = st1; dst[t + 1024] = st2; dst[t + 1536] = st3;
    }
    LGKM0();   // h0 staged AND st regs free
    {
      const float4* src = V4 + (size_t)g * 4096 + 2048;    // half 1
      st0 = src[t]; st1 = src[t + 512]; st2 = src[t + 1024]; st3 = src[t + 1536];
      size_t rb = rbase + (size_t)gn * 64;
      p0 = P4[rb]; q0 = Q4[rb];
      p1 = P4[rb + 2048]; q1 = Q4[rb + 2048];
      p2 = P4[rb + 4096]; q2 = Q4[rb + 4096];
      p3 = P4[rb + 6144]; q3 = Q4[rb + 6144];
    }
    __builtin_amdgcn_sched_barrier(0);
    if (w < 4) {
      int jw = w;   // combined 64x64 tile: rows 0-31 mask, rows 32-63 sign
      u64 A = (lane < 32) ? lms[par][lane][jw][0] : lms[par][lane - 32][jw][1];
#define BSTEP(J, M)                                          \
      {                                                      \
        u64 B = shflx64(A, J);                               \
        u64 keep = (lane & J) ? ~(u64)(M) : (u64)(M);        \
        u64 B2 = (lane & J) ? (B >> J) : (B << J);           \
        A = (A & keep) | (B2 & ~keep);                       \
      }
      BSTEP(32, 0x00000000FFFFFFFFULL)
      BSTEP(16, 0x0000FFFF0000FFFFULL)
      BSTEP(8,  0x00FF00FF00FF00FFULL)
      BSTEP(4,  0x0F0F0F0F0F0F0F0FULL)
      BSTEP(2,  0x3333333333333333ULL)
      BSTEP(1,  0x5555555555555555ULL)
#undef BSTEP
      int v = (g << 8) + (lane << 2) + jw;
      __builtin_nontemporal_store(A, &vbs[((size_t)v * 512 + cb) * 2 + h]);
    }
    LGKM0();   // transpose lms reads done (they complete before A anyway)
    SBAR();                                        // BAR2: h0 staged

    // ---- ph3: gather h0 (bits l<32) ----
#pragma unroll
    for (int i = 0; i < 4; ++i) {
      int cl = w * 4 + i;
#pragma unroll
      for (int j = 0; j < 4; ++j) {
        u64 m = readfl64(lms[par][cl][j][0]) & 0xffffffffULL;
        u64 sg = readfl64(lms[par][cl][j][1]);
        while (m) {
          int l = __builtin_ctzll(m);
          m &= m - 1;
          float dv = sbuf[(l * 4 + j) * 64 + lane];
          acc[i] += ((sg >> l) & 1) ? -(double)dv : (double)dv;
        }
      }
    }
    LGKM0();
    SBAR();                                        // BAR3: h0 reads done

    // ---- ph4: write sbuf h1 (compiler waits counted vmcnt for st) ----
    {
      float4* dst = (float4*)sbuf;
      dst[t] = st0; dst[t + 512] = st1; dst[t + 1024] = st2; dst[t + 1536] = st3;
    }
    LGKM0();
    SBAR();                                        // BAR4: h1 staged

    // ---- ph5: issue stage-h0(g+1); gather h1 (bits l>=32) ----
    {
      const float4* src = V4 + (size_t)gn * 4096;          // next half 0
      st0 = src[t]; st1 = src[t + 512]; st2 = src[t + 1024]; st3 = src[t + 1536];
    }
    __builtin_amdgcn_sched_barrier(0);
#pragma unroll
    for (int i = 0; i < 4; ++i) {
      int cl = w * 4 + i;
#pragma unroll
      for (int j = 0; j < 4; ++j) {
        u64 m = readfl64(lms[par][cl][j][0]) >> 32;
        u64 sg = readfl64(lms[par][cl][j][1]) >> 32;
        while (m) {
          int l = __builtin_ctzll(m);
          m &= m - 1;
          float dv = sbuf[(l * 4 + j) * 64 + lane];
          acc[i] += ((sg >> l) & 1) ? -(double)dv : (double)dv;
        }
      }
    }
    LGKM0();
    // next BAR1 protects sbuf from ph2(g+1) overwrite
  }
  __syncthreads();   // full drain before sbuf reuse in epilogue

  // ---- epilogue: relu + dmat = c @ fb1^T (sbuf reused: fbt + crow) ----
#pragma unroll
  for (int i2 = 0; i2 < 8; ++i2) {
    int idx = i2 * 512 + t;                      // idx = d*64+k
    sbuf[(idx & 63) * 64 + (idx >> 6)] = fb1[idx];
  }
  float* crow = sbuf + 4096 + w * 64;
  __syncthreads();
  for (int i = 0; i < 4; ++i) {
    float cv = fmaxf((float)acc[i] + cbias[lane], 0.f);
    crow[lane] = cv;
    __syncthreads();
    double da = 0.0;
#pragma unroll
    for (int k = 0; k < 64; ++k)
      da = fma((double)crow[k], (double)sbuf[k * 64 + lane], da);
    dmat[(size_t)(c0 + w * 4 + i) * 64 + lane] = (float)da;
    __syncthreads();
  }
}

// pass 2: decode masks -> LDS clause list, then 8-deep MLP gather.
__global__ __launch_bounds__(256, 8) void k_gather4(const u64* __restrict__ vbs,
                                                    const float* __restrict__ dmat,
                                                    double* __restrict__ nvd) {
  __shared__ __align__(16) unsigned short list[4][LCAP];
  int w = __builtin_amdgcn_readfirstlane(threadIdx.x >> 6);
  int lane = threadIdx.x & 63;
  int seg = blockIdx.x >> 11;              // 0..GSEG-1 (changes slowest)
  int v = (blockIdx.x & 2047) * 4 + w;
  int cc0 = seg * (512 / GSEG);
  const u64* P = vbs + ((size_t)v * 512 + cc0) * 2;
  u64 a0 = P[lane * 4 + 0], a1 = P[lane * 4 + 1];
  u64 b0 = P[lane * 4 + 2], b1 = P[lane * 4 + 3];
  u64 m0 = (a0 & 0xffffffffULL) | (a1 << 32);
  u64 s0 = (a0 >> 32) | (a1 & 0xffffffff00000000ULL);
  u64 m1 = (b0 & 0xffffffffULL) | (b1 << 32);
  u64 s1 = (b0 >> 32) | (b1 & 0xffffffff00000000ULL);
  int cnt = __popcll(m0) + __popcll(m1);
  int pre = cnt;
#pragma unroll
  for (int d = 1; d < 64; d <<= 1) {
    int o = __shfl_up(pre, d, 64);
    if (lane >= d) pre += o;
  }
  int tot = __shfl(pre, 63, 64);
  int base = pre - cnt;
#pragma unroll
  for (int half = 0; half < 2; ++half) {
    u64 m = half ? m1 : m0;
    u64 s = half ? s1 : s0;
    int cbase = (cc0 + 2 * lane + half) * 64;
    while (m) {
      int b = __builtin_ctzll(m);
      m &= m - 1;
      if (base < LCAP)
        list[w][base] = (unsigned short)((cbase + b) | (((s >> b) & 1) << 15));
      ++base;
    }
  }
  __syncthreads();
  if (tot > LCAP) tot = LCAP;
  const u64* lp = (const u64*)&list[w][0];
  double acc = 0.0;
  int k = 0;
  for (; k + 8 <= tot; k += 8) {
    u64 L0 = lp[k >> 2], L1 = lp[(k >> 2) + 1];
    unsigned e[8];
#pragma unroll
    for (int q = 0; q < 4; ++q) {
      e[q] = (unsigned)(L0 >> (16 * q)) & 0xffffu;
      e[4 + q] = (unsigned)(L1 >> (16 * q)) & 0xffffu;
    }
    float dv[8];
#pragma unroll
    for (int q = 0; q < 8; ++q)
      dv[q] = dmat[(size_t)(e[q] & 0x7fffu) * 64 + lane];
#pragma unroll
    for (int q = 0; q < 8; ++q)
      acc += (e[q] & 0x8000u) ? -(double)dv[q] : (double)dv[q];
  }
  for (; k < tot; ++k) {
    unsigned e = list[w][k];
    float dv = dmat[(size_t)(e & 0x7fffu) * 64 + lane];
    acc += (e & 0x8000u) ? -(double)dv : (double)dv;
  }
  atomicAdd(&nvd[(size_t)v * 64 + lane], acc);
}

// ======================= FALLBACK PATH (ws too small) =======================
__global__ __launch_bounds__(256) void k_pass1_basic(
    const float* __restrict__ pos, const float* __restrict__ neg,
    const float* __restrict__ bmat, const float* __restrict__ fb1,
    const float* __restrict__ cbias, float* __restrict__ dmat) {
  __shared__ float fbt[64 * 64];
  __shared__ float crow[4][64];
  int t = threadIdx.x;
#pragma unroll
  for (int i = 0; i < 16; ++i) {
    int idx = i * 256 + t;
    fbt[(idx & 63) * 64 + (idx >> 6)] = fb1[idx];
  }
  __syncthreads();
  int w = t >> 6, lane = t & 63;
  int c = blockIdx.x * 4 + w;
  const float4* prow = (const float4*)(pos + (size_t)c * NVAR);
  const float4* nrow = (const float4*)(neg + (size_t)c * NVAR);
  double acc = 0.0;
  for (int g = 0; g < 32; ++g) {
    float4 p = prow[g * 64 + lane];
    float4 q = nrow[g * 64 + lane];
    float sc[4];
    sc[0] = p.x - q.x; sc[1] = p.y - q.y; sc[2] = p.z - q.z; sc[3] = p.w - q.w;
#pragma unroll
    for (int j = 0; j < 4; ++j) {
      float s = sc[j];
      u64 m = __ballot(s != 0.f);
      u64 sg = __ballot(s < 0.f);
      while (m) {
        int l = __builtin_ctzll(m);
        m &= m - 1;
        float dv = bmat[(size_t)((g << 8) + (l << 2) + j) * 64 + lane];
        acc += ((sg >> l) & 1) ? -(double)dv : (double)dv;
      }
    }
  }
  float cv = fmaxf((float)acc + cbias[lane], 0.f);
  crow[w][lane] = cv;
  __syncthreads();
  double da = 0.0;
#pragma unroll
  for (int k = 0; k < 64; ++k)
    da = fma((double)crow[w][k], (double)fbt[k * 64 + lane], da);
  dmat[(size_t)c * 64 + lane] = (float)da;
}

__global__ __launch_bounds__(256) void k_pass2_dense(
    const float* __restrict__ pos, const float* __restrict__ neg,
    const float* __restrict__ dmat, double* __restrict__ nvd) {
  __shared__ float acc[64 * 64];
  int t = threadIdx.x;
#pragma unroll
  for (int i = 0; i < 16; ++i) acc[i * 256 + t] = 0.f;
  __syncthreads();
  int w = t >> 6, lane = t & 63;
  int s = blockIdx.x / CSEG, seg = blockIdx.x % CSEG;
  int c0 = seg * (NCLS / CSEG);
  for (int c = c0 + w; c < c0 + NCLS / CSEG; c += 4) {
    float p = pos[(size_t)c * NVAR + (s << 6) + lane];
    float q = neg[(size_t)c * NVAR + (s << 6) + lane];
    float sv = p - q;
    u64 m = __ballot(sv != 0.f);
    if (!m) continue;
    float dv = dmat[(size_t)c * 64 + lane];
    while (m) {
      int l = __builtin_ctzll(m);
      m &= m - 1;
      float sl = lane_bc(sv, l);
      atomicAdd(&acc[(l << 6) + lane], sl * dv);
    }
  }
  __syncthreads();
  size_t obase = (size_t)s * 4096;
#pragma unroll
  for (int i = 0; i < 16; ++i) {
    int idx = i * 256 + t;
    atomicAdd(&nvd[obase + idx], (double)acc[idx]);
  }
}

// ------- fused tail: ground-combiner + full GRU -------
__global__ __launch_bounds__(256, 1) void k_tailfused(
    const double* __restrict__ nvd, const float* __restrict__ vb,
    const float* __restrict__ ground, const float* __restrict__ Wg,
    const float* __restrict__ bg,
    const float* __restrict__ Wz, const float* __restrict__ Uz,
    const float* __restrict__ bz,
    const float* __restrict__ Wr, const float* __restrict__ Ur,
    const float* __restrict__ br,
    const float* __restrict__ Wh, const float* __restrict__ Uh,
    const float* __restrict__ bh,
    const float* __restrict__ prev, float* __restrict__ out) {
  __shared__ float wg[72 * 65];
  __shared__ float wz[64 * 65], uz[64 * 65], wr[64 * 65], ur[64 * 65],
      wh[64 * 65], uh[64 * 65];
  __shared__ float xrow[4][72], yrow[4][64], prow[4][64], rprow[4][64];
  int t = threadIdx.x;
#pragma unroll
  for (int i = 0; i < 18; ++i) {
    int idx = i * 256 + t;
    wg[(idx % 72) * 65 + (idx / 72)] = Wg[idx];
  }
#pragma unroll
  for (int i = 0; i < 16; ++i) {
    int idx = i * 256 + t;
    int a = (idx & 63) * 65 + (idx >> 6);
    wz[a] = Wz[idx]; uz[a] = Uz[idx]; wr[a] = Wr[idx];
    ur[a] = Ur[idx]; wh[a] = Wh[idx]; uh[a] = Uh[idx];
  }
  __syncthreads();
  int w = t >> 6, lane = t & 63;
  for (int rr = 0; rr < 8; ++rr) {
    int row = blockIdx.x * 32 + w * 8 + rr;
    float pv = prev[row * 64 + lane];
    float ve = fmaxf((float)nvd[row * 64 + lane] + vb[lane], 0.f);
    xrow[w][8 + lane] = ve;
    if (lane < 8) xrow[w][lane] = ground[row * 8 + lane];
    prow[w][lane] = pv;
    double a = 0.0;
#pragma unroll
    for (int k = 0; k < 72; ++k)
      a = fma((double)xrow[w][k], (double)wg[k * 65 + lane], a);
    float ve2 = tanhf((float)a + bg[lane]);
    yrow[w][lane] = ve2;
    float az = bz[lane], ar = br[lane];
#pragma unroll
    for (int k = 0; k < 64; ++k) {
      float y = yrow[w][k], p = prow[w][k];
      az = fmaf(y, wz[k * 65 + lane], az);
      az = fmaf(p, uz[k * 65 + lane], az);
      ar = fmaf(y, wr[k * 65 + lane], ar);
      ar = fmaf(p, ur[k * 65 + lane], ar);
    }
    float r = 1.f / (1.f + expf(-ar));
    rprow[w][lane] = r * pv;
    float ah = bh[lane];
#pragma unroll
    for (int k = 0; k < 64; ++k) {
      ah = fmaf(yrow[w][k], wh[k * 65 + lane], ah);
      ah = fmaf(rprow[w][k], uh[k * 65 + lane], ah);
    }
    float z = 1.f / (1.f + expf(-az));
    float hh = tanhf(ah);
    out[row * 64 + lane] = (1.f - z) * pv + z * hh;
  }
}

extern "C" void kernel_launch(void* const* d_in, const int* in_sizes, int n_in,
                              void* d_out, int out_size, void* d_ws, size_t ws_size,
                              hipStream_t stream) {
  const float* variables = (const float*)d_in[0];
  const float* ground    = (const float*)d_in[1];
  const float* cpos      = (const float*)d_in[2];
  const float* cneg      = (const float*)d_in[3];
  const float* fb        = (const float*)d_in[6];
  const float* vb        = (const float*)d_in[7];
  const float* cb        = (const float*)d_in[8];
  const float* Wg        = (const float*)d_in[9];
  const float* bg        = (const float*)d_in[10];
  const float* Wz        = (const float*)d_in[11];
  const float* Uz        = (const float*)d_in[12];
  const float* bz        = (const float*)d_in[13];
  const float* Wr        = (const float*)d_in[14];
  const float* Ur        = (const float*)d_in[15];
  const float* br        = (const float*)d_in[16];
  const float* Wh        = (const float*)d_in[17];
  const float* Uh        = (const float*)d_in[18];
  const float* bh        = (const float*)d_in[19];
  float* out = (float*)d_out;
  char* ws = (char*)d_ws;
  const size_t MB = (size_t)1 << 20;

  float* vfwd   = (float*)(ws + 0);        // 2 MB
  float* dmat   = (float*)(ws + 2 * MB);   // 8 MB
  double* nvd   = (double*)(ws + 10 * MB); // 4 MB (f64 accumulator)
  u64* vbs      = (u64*)(ws + 16 * MB);    // 64 MB: [var][512][2]
  bool fast = ws_size >= 80 * MB;

  k_varsfwd<<<512, 256, 0, stream>>>(variables, fb, vfwd);
  hipMemsetAsync(nvd, 0, (size_t)NVAR * 64 * sizeof(double), stream);
  if (fast) {
    k_pass1v5<<<1024, 512, 0, stream>>>(cpos, cneg, vfwd, fb + 4096, cb, dmat,
                                        vbs);
    k_gather4<<<2048 * GSEG, 256, 0, stream>>>(vbs, dmat, nvd);
  } else {
    k_pass1_basic<<<8192, 256, 0, stream>>>(cpos, cneg, vfwd, fb + 4096, cb, dmat);
    k_pass2_dense<<<128 * CSEG, 256, 0, stream>>>(cpos, cneg, dmat, nvd);
  }
  k_tailfused<<<256, 256, 0, stream>>>(nvd, vb, ground, Wg, bg, Wz, Uz, bz,
                                       Wr, Ur, br, Wh, Uh, bh, variables, out);
}

// Round 10
// 828.122 us; speedup vs baseline: 1.6997x; 1.6997x over previous
//
#include <hip/hip_runtime.h>
#include <stdint.h>

typedef unsigned long long u64;

#define NVAR 8192
#define NCLS 32768
#define CSEG 16
#define GSEG 4           // gather segments (128 chunks each)
#define LCAP 1152        // per-warp gather list capacity

__device__ __forceinline__ float lane_bc(float v, int l) { return __shfl(v, l); }

__device__ __forceinline__ u64 readfl64(u64 x) {
  unsigned lo = __builtin_amdgcn_readfirstlane((unsigned)x);
  unsigned hi = __builtin_amdgcn_readfirstlane((unsigned)(x >> 32));
  return ((u64)hi << 32) | (u64)lo;
}

__device__ __forceinline__ u64 shflx64(u64 x, int m) {
  unsigned lo = (unsigned)__shfl_xor((int)(unsigned)x, m, 64);
  unsigned hi = (unsigned)__shfl_xor((int)(unsigned)(x >> 32), m, 64);
  return ((u64)hi << 32) | (u64)lo;
}

// ---------------- kernel 1: vars_fwd = v @ fb0^T  [NVAR,64] ----------------
__global__ __launch_bounds__(256) void k_varsfwd(const float* __restrict__ v,
                                                 const float* __restrict__ fb0,
                                                 float* __restrict__ out) {
  __shared__ float fbt[64 * 64];   // fbt[k][d] = fb0[d][k]
  __shared__ float vrow[4][64];
  int t = threadIdx.x;
#pragma unroll
  for (int i = 0; i < 16; ++i) {
    int idx = i * 256 + t;                       // idx = d*64+k
    fbt[(idx & 63) * 64 + (idx >> 6)] = fb0[idx];
  }
  __syncthreads();
  int w = t >> 6, lane = t & 63;
  for (int rr = 0; rr < 16; rr += 4) {
    int row = blockIdx.x * 16 + rr + w;
    vrow[w][lane] = v[row * 64 + lane];
    __syncthreads();
    double a = 0.0;
#pragma unroll
    for (int k = 0; k < 64; ++k)
      a = fma((double)vrow[w][k], (double)fbt[k * 64 + lane], a);
    out[row * 64 + lane] = (float)a;
    __syncthreads();
  }
}

// ======================= FAST PATH =======================
// pass 1 (round-6 structure + XCD-chunked swizzle): block = 32 clauses.
// Reg-prefetched LDS staging of vfwd; butterfly bit-transpose (4 warps)
// emitting vbs[var][cc][h] u64 = {lo32: presence, hi32: sign}.
// Swizzle: the 16 blocks sharing each 128B vbs line run on ONE XCD so the
// line merges in that XCD's L2 (kills write-allocate fill + write amp).
__global__ __launch_bounds__(512, 8) void k_pass1v6(
    const float* __restrict__ pos, const float* __restrict__ neg,
    const float* __restrict__ vfwd, const float* __restrict__ fb1,
    const float* __restrict__ cbias, float* __restrict__ dmat,
    u64* __restrict__ vbs) {
  __shared__ float sbuf[128 * 64];        // 32KB staging; epilogue: fbt+crow
  __shared__ u64 lm[2][32][4];            // double-buffered presence masks
  __shared__ u64 lsg[2][32][4];           // sign masks
  int t = threadIdx.x;
  int w = __builtin_amdgcn_readfirstlane(t >> 6);   // warp 0..7
  int lane = t & 63;
  int orig = blockIdx.x;           // 0..1023, round-robin across 8 XCDs
  int bx = ((orig & 7) << 7) + (orig >> 3);   // chunk per XCD (bijective)
  int c0 = bx * 32;                // first clause
  int cb = bx >> 1;                // 64-clause chunk
  int h = bx & 1;                  // which u64 slot (32-clause half)
  double acc[4];
#pragma unroll
  for (int i = 0; i < 4; ++i) acc[i] = 0.0;

  for (int g = 0; g < 32; ++g) {   // 256-var groups
    int par = g & 1;
    // ---- ph1: issue h0 stage loads; stream pos/neg; ballots -> lm/lsg ----
    const float4* s0 = (const float4*)(vfwd + (size_t)g * 256 * 64);
    float4 st0 = s0[t], st1 = s0[t + 512], st2 = s0[t + 1024], st3 = s0[t + 1536];
#pragma unroll
    for (int i = 0; i < 4; i += 2) {
      size_t rb0 = (size_t)(c0 + w * 4 + i) * 2048 + (size_t)g * 64 + lane;
      size_t rb1 = rb0 + 2048;
      float4 p0 = ((const float4*)pos)[rb0];
      float4 q0 = ((const float4*)neg)[rb0];
      float4 p1 = ((const float4*)pos)[rb1];
      float4 q1 = ((const float4*)neg)[rb1];
      float a0[4], a1[4];
      a0[0] = p0.x - q0.x; a0[1] = p0.y - q0.y; a0[2] = p0.z - q0.z; a0[3] = p0.w - q0.w;
      a1[0] = p1.x - q1.x; a1[1] = p1.y - q1.y; a1[2] = p1.z - q1.z; a1[3] = p1.w - q1.w;
      int cl0 = w * 4 + i, cl1 = cl0 + 1;
#pragma unroll
      for (int j = 0; j < 4; ++j) {
        u64 m = __ballot(a0[j] != 0.f);
        u64 sg = __ballot(a0[j] < 0.f);
        if (lane == j) { lm[par][cl0][j] = m; lsg[par][cl0][j] = sg; }
      }
#pragma unroll
      for (int j = 0; j < 4; ++j) {
        u64 m = __ballot(a1[j] != 0.f);
        u64 sg = __ballot(a1[j] < 0.f);
        if (lane == j) { lm[par][cl1][j] = m; lsg[par][cl1][j] = sg; }
      }
    }
    __syncthreads();   // BAR1 (also drains h0 stage loads)

    // ---- ph2: write sbuf h0; warps 0-3 butterfly-transpose (mask+sign) ----
    {
      float4* dst = (float4*)sbuf;
      dst[t] = st0; dst[t + 512] = st1; dst[t + 1024] = st2; dst[t + 1536] = st3;
    }
    if (w < 4) {
      int jw = w;   // combined 64x64 tile: rows 0-31 mask, rows 32-63 sign
      u64 A = (lane < 32) ? lm[par][lane][jw] : lsg[par][lane - 32][jw];
#define BSTEP(J, M)                                          \
      {                                                      \
        u64 B = shflx64(A, J);                               \
        u64 keep = (lane & J) ? ~(u64)(M) : (u64)(M);        \
        u64 B2 = (lane & J) ? (B >> J) : (B << J);           \
        A = (A & keep) | (B2 & ~keep);                       \
      }
      BSTEP(32, 0x00000000FFFFFFFFULL)
      BSTEP(16, 0x0000FFFF0000FFFFULL)
      BSTEP(8,  0x00FF00FF00FF00FFULL)
      BSTEP(4,  0x0F0F0F0F0F0F0F0FULL)
      BSTEP(2,  0x3333333333333333ULL)
      BSTEP(1,  0x5555555555555555ULL)
#undef BSTEP
      int v = (g << 8) + (lane << 2) + jw;
      vbs[((size_t)v * 512 + cb) * 2 + h] = A;   // {lo: mask32, hi: sign32}
    }
    __syncthreads();   // BAR2: h0 staged

    // ---- ph3: issue h1 stage loads; gather h0 (bits l<32) ----
    const float4* s1 = s0 + 2048;
    st0 = s1[t]; st1 = s1[t + 512]; st2 = s1[t + 1024]; st3 = s1[t + 1536];
#pragma unroll
    for (int i = 0; i < 4; ++i) {
      int cl = w * 4 + i;
#pragma unroll
      for (int j = 0; j < 4; ++j) {
        u64 m = readfl64(lm[par][cl][j]) & 0xffffffffULL;
        u64 sg = readfl64(lsg[par][cl][j]);
        while (m) {
          int l = __builtin_ctzll(m);
          m &= m - 1;
          float dv = sbuf[(l * 4 + j) * 64 + lane];
          acc[i] += ((sg >> l) & 1) ? -(double)dv : (double)dv;
        }
      }
    }
    __syncthreads();   // BAR3: gather0 done (drains h1 loads)

    // ---- ph4: write sbuf h1 ----
    {
      float4* dst = (float4*)sbuf;
      dst[t] = st0; dst[t + 512] = st1; dst[t + 1024] = st2; dst[t + 1536] = st3;
    }
    __syncthreads();   // BAR4: h1 staged

    // ---- ph5: gather h1 (bits l>=32); lm double-buffered -> no tail bar ----
#pragma unroll
    for (int i = 0; i < 4; ++i) {
      int cl = w * 4 + i;
#pragma unroll
      for (int j = 0; j < 4; ++j) {
        u64 m = readfl64(lm[par][cl][j]) >> 32;
        u64 sg = readfl64(lsg[par][cl][j]) >> 32;
        while (m) {
          int l = __builtin_ctzll(m);
          m &= m - 1;
          float dv = sbuf[(l * 4 + j) * 64 + lane];
          acc[i] += ((sg >> l) & 1) ? -(double)dv : (double)dv;
        }
      }
    }
  }
  __syncthreads();   // protect sbuf reuse in epilogue

  // ---- epilogue: relu + dmat = c @ fb1^T (sbuf reused: fbt + crow) ----
#pragma unroll
  for (int i2 = 0; i2 < 8; ++i2) {
    int idx = i2 * 512 + t;                      // idx = d*64+k
    sbuf[(idx & 63) * 64 + (idx >> 6)] = fb1[idx];
  }
  float* crow = sbuf + 4096 + w * 64;
  __syncthreads();
  for (int i = 0; i < 4; ++i) {
    float cv = fmaxf((float)acc[i] + cbias[lane], 0.f);
    crow[lane] = cv;
    __syncthreads();
    double da = 0.0;
#pragma unroll
    for (int k = 0; k < 64; ++k)
      da = fma((double)crow[k], (double)sbuf[k * 64 + lane], da);
    dmat[(size_t)(c0 + w * 4 + i) * 64 + lane] = (float)da;
    __syncthreads();
  }
}

// pass 2: decode masks -> LDS clause list, then 8-deep MLP gather.
// grid = GSEG * 2048 seg-major (2MB dmat slice per seg stays L2-resident).
__global__ __launch_bounds__(256, 8) void k_gather4(const u64* __restrict__ vbs,
                                                    const float* __restrict__ dmat,
                                                    double* __restrict__ nvd) {
  __shared__ __align__(16) unsigned short list[4][LCAP];
  int w = __builtin_amdgcn_readfirstlane(threadIdx.x >> 6);
  int lane = threadIdx.x & 63;
  int seg = blockIdx.x >> 11;              // 0..GSEG-1 (changes slowest)
  int v = (blockIdx.x & 2047) * 4 + w;
  int cc0 = seg * (512 / GSEG);
  const u64* P = vbs + ((size_t)v * 512 + cc0) * 2;
  u64 a0 = P[lane * 4 + 0], a1 = P[lane * 4 + 1];
  u64 b0 = P[lane * 4 + 2], b1 = P[lane * 4 + 3];
  u64 m0 = (a0 & 0xffffffffULL) | (a1 << 32);
  u64 s0 = (a0 >> 32) | (a1 & 0xffffffff00000000ULL);
  u64 m1 = (b0 & 0xffffffffULL) | (b1 << 32);
  u64 s1 = (b0 >> 32) | (b1 & 0xffffffff00000000ULL);
  int cnt = __popcll(m0) + __popcll(m1);
  int pre = cnt;
#pragma unroll
  for (int d = 1; d < 64; d <<= 1) {
    int o = __shfl_up(pre, d, 64);
    if (lane >= d) pre += o;
  }
  int tot = __shfl(pre, 63, 64);
  int base = pre - cnt;
#pragma unroll
  for (int half = 0; half < 2; ++half) {
    u64 m = half ? m1 : m0;
    u64 s = half ? s1 : s0;
    int cbase = (cc0 + 2 * lane + half) * 64;
    while (m) {
      int b = __builtin_ctzll(m);
      m &= m - 1;
      if (base < LCAP)
        list[w][base] = (unsigned short)((cbase + b) | (((s >> b) & 1) << 15));
      ++base;
    }
  }
  __syncthreads();
  if (tot > LCAP) tot = LCAP;
  const u64* lp = (const u64*)&list[w][0];
  double acc = 0.0;
  int k = 0;
  for (; k + 8 <= tot; k += 8) {
    u64 L0 = lp[k >> 2], L1 = lp[(k >> 2) + 1];
    unsigned e[8];
#pragma unroll
    for (int q = 0; q < 4; ++q) {
      e[q] = (unsigned)(L0 >> (16 * q)) & 0xffffu;
      e[4 + q] = (unsigned)(L1 >> (16 * q)) & 0xffffu;
    }
    float dv[8];
#pragma unroll
    for (int q = 0; q < 8; ++q)
      dv[q] = dmat[(size_t)(e[q] & 0x7fffu) * 64 + lane];
#pragma unroll
    for (int q = 0; q < 8; ++q)
      acc += (e[q] & 0x8000u) ? -(double)dv[q] : (double)dv[q];
  }
  for (; k < tot; ++k) {
    unsigned e = list[w][k];
    float dv = dmat[(size_t)(e & 0x7fffu) * 64 + lane];
    acc += (e & 0x8000u) ? -(double)dv : (double)dv;
  }
  atomicAdd(&nvd[(size_t)v * 64 + lane], acc);
}

// ======================= FALLBACK PATH (ws too small) =======================
__global__ __launch_bounds__(256) void k_pass1_basic(
    const float* __restrict__ pos, const float* __restrict__ neg,
    const float* __restrict__ bmat, const float* __restrict__ fb1,
    const float* __restrict__ cbias, float* __restrict__ dmat) {
  __shared__ float fbt[64 * 64];
  __shared__ float crow[4][64];
  int t = threadIdx.x;
#pragma unroll
  for (int i = 0; i < 16; ++i) {
    int idx = i * 256 + t;
    fbt[(idx & 63) * 64 + (idx >> 6)] = fb1[idx];
  }
  __syncthreads();
  int w = t >> 6, lane = t & 63;
  int c = blockIdx.x * 4 + w;
  const float4* prow = (const float4*)(pos + (size_t)c * NVAR);
  const float4* nrow = (const float4*)(neg + (size_t)c * NVAR);
  double acc = 0.0;
  for (int g = 0; g < 32; ++g) {
    float4 p = prow[g * 64 + lane];
    float4 q = nrow[g * 64 + lane];
    float sc[4];
    sc[0] = p.x - q.x; sc[1] = p.y - q.y; sc[2] = p.z - q.z; sc[3] = p.w - q.w;
#pragma unroll
    for (int j = 0; j < 4; ++j) {
      float s = sc[j];
      u64 m = __ballot(s != 0.f);
      u64 sg = __ballot(s < 0.f);
      while (m) {
        int l = __builtin_ctzll(m);
        m &= m - 1;
        float dv = bmat[(size_t)((g << 8) + (l << 2) + j) * 64 + lane];
        acc += ((sg >> l) & 1) ? -(double)dv : (double)dv;
      }
    }
  }
  float cv = fmaxf((float)acc + cbias[lane], 0.f);
  crow[w][lane] = cv;
  __syncthreads();
  double da = 0.0;
#pragma unroll
  for (int k = 0; k < 64; ++k)
    da = fma((double)crow[w][k], (double)fbt[k * 64 + lane], da);
  dmat[(size_t)c * 64 + lane] = (float)da;
}

__global__ __launch_bounds__(256) void k_pass2_dense(
    const float* __restrict__ pos, const float* __restrict__ neg,
    const float* __restrict__ dmat, double* __restrict__ nvd) {
  __shared__ float acc[64 * 64];
  int t = threadIdx.x;
#pragma unroll
  for (int i = 0; i < 16; ++i) acc[i * 256 + t] = 0.f;
  __syncthreads();
  int w = t >> 6, lane = t & 63;
  int s = blockIdx.x / CSEG, seg = blockIdx.x % CSEG;
  int c0 = seg * (NCLS / CSEG);
  for (int c = c0 + w; c < c0 + NCLS / CSEG; c += 4) {
    float p = pos[(size_t)c * NVAR + (s << 6) + lane];
    float q = neg[(size_t)c * NVAR + (s << 6) + lane];
    float sv = p - q;
    u64 m = __ballot(sv != 0.f);
    if (!m) continue;
    float dv = dmat[(size_t)c * 64 + lane];
    while (m) {
      int l = __builtin_ctzll(m);
      m &= m - 1;
      float sl = lane_bc(sv, l);
      atomicAdd(&acc[(l << 6) + lane], sl * dv);
    }
  }
  __syncthreads();
  size_t obase = (size_t)s * 4096;
#pragma unroll
  for (int i = 0; i < 16; ++i) {
    int idx = i * 256 + t;
    atomicAdd(&nvd[obase + idx], (double)acc[idx]);
  }
}

// ------- fused tail: ground-combiner + full GRU -------
__global__ __launch_bounds__(256, 1) void k_tailfused(
    const double* __restrict__ nvd, const float* __restrict__ vb,
    const float* __restrict__ ground, const float* __restrict__ Wg,
    const float* __restrict__ bg,
    const float* __restrict__ Wz, const float* __restrict__ Uz,
    const float* __restrict__ bz,
    const float* __restrict__ Wr, const float* __restrict__ Ur,
    const float* __restrict__ br,
    const float* __restrict__ Wh, const float* __restrict__ Uh,
    const float* __restrict__ bh,
    const float* __restrict__ prev, float* __restrict__ out) {
  __shared__ float wg[72 * 65];
  __shared__ float wz[64 * 65], uz[64 * 65], wr[64 * 65], ur[64 * 65],
      wh[64 * 65], uh[64 * 65];
  __shared__ float xrow[4][72], yrow[4][64], prow[4][64], rprow[4][64];
  int t = threadIdx.x;
#pragma unroll
  for (int i = 0; i < 18; ++i) {
    int idx = i * 256 + t;
    wg[(idx % 72) * 65 + (idx / 72)] = Wg[idx];
  }
#pragma unroll
  for (int i = 0; i < 16; ++i) {
    int idx = i * 256 + t;
    int a = (idx & 63) * 65 + (idx >> 6);
    wz[a] = Wz[idx]; uz[a] = Uz[idx]; wr[a] = Wr[idx];
    ur[a] = Ur[idx]; wh[a] = Wh[idx]; uh[a] = Uh[idx];
  }
  __syncthreads();
  int w = t >> 6, lane = t & 63;
  for (int rr = 0; rr < 8; ++rr) {
    int row = blockIdx.x * 32 + w * 8 + rr;
    float pv = prev[row * 64 + lane];
    float ve = fmaxf((float)nvd[row * 64 + lane] + vb[lane], 0.f);
    xrow[w][8 + lane] = ve;
    if (lane < 8) xrow[w][lane] = ground[row * 8 + lane];
    prow[w][lane] = pv;
    double a = 0.0;
#pragma unroll
    for (int k = 0; k < 72; ++k)
      a = fma((double)xrow[w][k], (double)wg[k * 65 + lane], a);
    float ve2 = tanhf((float)a + bg[lane]);
    yrow[w][lane] = ve2;
    float az = bz[lane], ar = br[lane];
#pragma unroll
    for (int k = 0; k < 64; ++k) {
      float y = yrow[w][k], p = prow[w][k];
      az = fmaf(y, wz[k * 65 + lane], az);
      az = fmaf(p, uz[k * 65 + lane], az);
      ar = fmaf(y, wr[k * 65 + lane], ar);
      ar = fmaf(p, ur[k * 65 + lane], ar);
    }
    float r = 1.f / (1.f + expf(-ar));
    rprow[w][lane] = r * pv;
    float ah = bh[lane];
#pragma unroll
    for (int k = 0; k < 64; ++k) {
      ah = fmaf(yrow[w][k], wh[k * 65 + lane], ah);
      ah = fmaf(rprow[w][k], uh[k * 65 + lane], ah);
    }
    float z = 1.f / (1.f + expf(-az));
    float hh = tanhf(ah);
    out[row * 64 + lane] = (1.f - z) * pv + z * hh;
  }
}

extern "C" void kernel_launch(void* const* d_in, const int* in_sizes, int n_in,
                              void* d_out, int out_size, void* d_ws, size_t ws_size,
                              hipStream_t stream) {
  const float* variables = (const float*)d_in[0];
  const float* ground    = (const float*)d_in[1];
  const float* cpos      = (const float*)d_in[2];
  const float* cneg      = (const float*)d_in[3];
  const float* fb        = (const float*)d_in[6];
  const float* vb        = (const float*)d_in[7];
  const float* cb        = (const float*)d_in[8];
  const float* Wg        = (const float*)d_in[9];
  const float* bg        = (const float*)d_in[10];
  const float* Wz        = (const float*)d_in[11];
  const float* Uz        = (const float*)d_in[12];
  const float* bz        = (const float*)d_in[13];
  const float* Wr        = (const float*)d_in[14];
  const float* Ur        = (const float*)d_in[15];
  const float* br        = (const float*)d_in[16];
  const float* Wh        = (const float*)d_in[17];
  const float* Uh        = (const float*)d_in[18];
  const float* bh        = (const float*)d_in[19];
  float* out = (float*)d_out;
  char* ws = (char*)d_ws;
  const size_t MB = (size_t)1 << 20;

  float* vfwd   = (float*)(ws + 0);        // 2 MB
  float* dmat   = (float*)(ws + 2 * MB);   // 8 MB
  double* nvd   = (double*)(ws + 10 * MB); // 4 MB (f64 accumulator)
  u64* vbs      = (u64*)(ws + 16 * MB);    // 64 MB: [var][512][2]
  bool fast = ws_size >= 80 * MB;

  k_varsfwd<<<512, 256, 0, stream>>>(variables, fb, vfwd);
  hipMemsetAsync(nvd, 0, (size_t)NVAR * 64 * sizeof(double), stream);
  if (fast) {
    k_pass1v6<<<1024, 512, 0, stream>>>(cpos, cneg, vfwd, fb + 4096, cb, dmat,
                                        vbs);
    k_gather4<<<2048 * GSEG, 256, 0, stream>>>(vbs, dmat, nvd);
  } else {
    k_pass1_basic<<<8192, 256, 0, stream>>>(cpos, cneg, vfwd, fb + 4096, cb, dmat);
    k_pass2_dense<<<128 * CSEG, 256, 0, stream>>>(cpos, cneg, dmat, nvd);
  }
  k_tailfused<<<256, 256, 0, stream>>>(nvd, vb, ground, Wg, bg, Wz, Uz, bz,
                                       Wr, Ur, br, Wh, Uh, bh, variables, out);
}

// Round 12
// 754.491 us; speedup vs baseline: 1.8656x; 1.0976x over previous
//
#include <hip/hip_runtime.h>
#include <stdint.h>

typedef unsigned long long u64;
typedef float f32x4 __attribute__((ext_vector_type(4)));

#define NVAR 8192
#define NCLS 32768
#define CSEG 16
#define GSEG 4           // gather segments (128 chunks each)
#define LCAP 1152        // per-warp gather list capacity

__device__ __forceinline__ float lane_bc(float v, int l) { return __shfl(v, l); }

__device__ __forceinline__ u64 readfl64(u64 x) {
  unsigned lo = __builtin_amdgcn_readfirstlane((unsigned)x);
  unsigned hi = __builtin_amdgcn_readfirstlane((unsigned)(x >> 32));
  return ((u64)hi << 32) | (u64)lo;
}

__device__ __forceinline__ u64 shflx64(u64 x, int m) {
  unsigned lo = (unsigned)__shfl_xor((int)(unsigned)x, m, 64);
  unsigned hi = (unsigned)__shfl_xor((int)(unsigned)(x >> 32), m, 64);
  return ((u64)hi << 32) | (u64)lo;
}

// ---------------- kernel 1: vars_fwd = v @ fb0^T  [NVAR,64] ----------------
__global__ __launch_bounds__(256) void k_varsfwd(const float* __restrict__ v,
                                                 const float* __restrict__ fb0,
                                                 float* __restrict__ out) {
  __shared__ float fbt[64 * 64];   // fbt[k][d] = fb0[d][k]
  __shared__ float vrow[4][64];
  int t = threadIdx.x;
#pragma unroll
  for (int i = 0; i < 16; ++i) {
    int idx = i * 256 + t;                       // idx = d*64+k
    fbt[(idx & 63) * 64 + (idx >> 6)] = fb0[idx];
  }
  __syncthreads();
  int w = t >> 6, lane = t & 63;
  for (int rr = 0; rr < 16; rr += 4) {
    int row = blockIdx.x * 16 + rr + w;
    vrow[w][lane] = v[row * 64 + lane];
    __syncthreads();
    double a = 0.0;
#pragma unroll
    for (int k = 0; k < 64; ++k)
      a = fma((double)vrow[w][k], (double)fbt[k * 64 + lane], a);
    out[row * 64 + lane] = (float)a;
    __syncthreads();
  }
}

// ======================= FAST PATH =======================
// pass 1 (round-10 structure + NT streaming loads): block = 32 clauses.
// XCD-chunked swizzle keeps the 16 writers of each 128B vbs line on one XCD.
// pos/neg read once -> nontemporal (keeps vfwd/vbs lines resident in L2).
__global__ __launch_bounds__(512, 8) void k_pass1v7(
    const float* __restrict__ pos, const float* __restrict__ neg,
    const float* __restrict__ vfwd, const float* __restrict__ fb1,
    const float* __restrict__ cbias, float* __restrict__ dmat,
    u64* __restrict__ vbs) {
  __shared__ float sbuf[128 * 64];        // 32KB staging; epilogue: fbt+crow
  __shared__ u64 lm[2][32][4];            // double-buffered presence masks
  __shared__ u64 lsg[2][32][4];           // sign masks
  int t = threadIdx.x;
  int w = __builtin_amdgcn_readfirstlane(t >> 6);   // warp 0..7
  int lane = t & 63;
  int orig = blockIdx.x;           // 0..1023, round-robin across 8 XCDs
  int bx = ((orig & 7) << 7) + (orig >> 3);   // chunk per XCD (bijective)
  int c0 = bx * 32;                // first clause
  int cb = bx >> 1;                // 64-clause chunk
  int h = bx & 1;                  // which u64 slot (32-clause half)
  double acc[4];
#pragma unroll
  for (int i = 0; i < 4; ++i) acc[i] = 0.0;

  for (int g = 0; g < 32; ++g) {   // 256-var groups
    int par = g & 1;
    // ---- ph1: issue h0 stage loads; NT-stream pos/neg; ballots ----
    const float4* s0 = (const float4*)(vfwd + (size_t)g * 256 * 64);
    float4 st0 = s0[t], st1 = s0[t + 512], st2 = s0[t + 1024], st3 = s0[t + 1536];
#pragma unroll
    for (int i = 0; i < 4; i += 2) {
      size_t rb0 = (size_t)(c0 + w * 4 + i) * 2048 + (size_t)g * 64 + lane;
      size_t rb1 = rb0 + 2048;
      f32x4 p0 = __builtin_nontemporal_load(&((const f32x4*)pos)[rb0]);
      f32x4 q0 = __builtin_nontemporal_load(&((const f32x4*)neg)[rb0]);
      f32x4 p1 = __builtin_nontemporal_load(&((const f32x4*)pos)[rb1]);
      f32x4 q1 = __builtin_nontemporal_load(&((const f32x4*)neg)[rb1]);
      f32x4 a0 = p0 - q0;
      f32x4 a1 = p1 - q1;
      int cl0 = w * 4 + i, cl1 = cl0 + 1;
#pragma unroll
      for (int j = 0; j < 4; ++j) {
        u64 m = __ballot(a0[j] != 0.f);
        u64 sg = __ballot(a0[j] < 0.f);
        if (lane == j) { lm[par][cl0][j] = m; lsg[par][cl0][j] = sg; }
      }
#pragma unroll
      for (int j = 0; j < 4; ++j) {
        u64 m = __ballot(a1[j] != 0.f);
        u64 sg = __ballot(a1[j] < 0.f);
        if (lane == j) { lm[par][cl1][j] = m; lsg[par][cl1][j] = sg; }
      }
    }
    __syncthreads();   // BAR1 (also drains h0 stage loads)

    // ---- ph2: write sbuf h0; warps 0-3 butterfly-transpose (mask+sign) ----
    {
      float4* dst = (float4*)sbuf;
      dst[t] = st0; dst[t + 512] = st1; dst[t + 1024] = st2; dst[t + 1536] = st3;
    }
    if (w < 4) {
      int jw = w;   // combined 64x64 tile: rows 0-31 mask, rows 32-63 sign
      u64 A = (lane < 32) ? lm[par][lane][jw] : lsg[par][lane - 32][jw];
#define BSTEP(J, M)                                          \
      {                                                      \
        u64 B = shflx64(A, J);                               \
        u64 keep = (lane & J) ? ~(u64)(M) : (u64)(M);        \
        u64 B2 = (lane & J) ? (B >> J) : (B << J);           \
        A = (A & keep) | (B2 & ~keep);                       \
      }
      BSTEP(32, 0x00000000FFFFFFFFULL)
      BSTEP(16, 0x0000FFFF0000FFFFULL)
      BSTEP(8,  0x00FF00FF00FF00FFULL)
      BSTEP(4,  0x0F0F0F0F0F0F0F0FULL)
      BSTEP(2,  0x3333333333333333ULL)
      BSTEP(1,  0x5555555555555555ULL)
#undef BSTEP
      int v = (g << 8) + (lane << 2) + jw;
      vbs[((size_t)v * 512 + cb) * 2 + h] = A;   // {lo: mask32, hi: sign32}
    }
    __syncthreads();   // BAR2: h0 staged

    // ---- ph3: issue h1 stage loads; gather h0 (bits l<32) ----
    const float4* s1 = s0 + 2048;
    st0 = s1[t]; st1 = s1[t + 512]; st2 = s1[t + 1024]; st3 = s1[t + 1536];
#pragma unroll
    for (int i = 0; i < 4; ++i) {
      int cl = w * 4 + i;
#pragma unroll
      for (int j = 0; j < 4; ++j) {
        u64 m = readfl64(lm[par][cl][j]) & 0xffffffffULL;
        u64 sg = readfl64(lsg[par][cl][j]);
        while (m) {
          int l = __builtin_ctzll(m);
          m &= m - 1;
          float dv = sbuf[(l * 4 + j) * 64 + lane];
          acc[i] += ((sg >> l) & 1) ? -(double)dv : (double)dv;
        }
      }
    }
    __syncthreads();   // BAR3: gather0 done (drains h1 loads)

    // ---- ph4: write sbuf h1 ----
    {
      float4* dst = (float4*)sbuf;
      dst[t] = st0; dst[t + 512] = st1; dst[t + 1024] = st2; dst[t + 1536] = st3;
    }
    __syncthreads();   // BAR4: h1 staged

    // ---- ph5: gather h1 (bits l>=32); lm double-buffered -> no tail bar ----
#pragma unroll
    for (int i = 0; i < 4; ++i) {
      int cl = w * 4 + i;
#pragma unroll
      for (int j = 0; j < 4; ++j) {
        u64 m = readfl64(lm[par][cl][j]) >> 32;
        u64 sg = readfl64(lsg[par][cl][j]) >> 32;
        while (m) {
          int l = __builtin_ctzll(m);
          m &= m - 1;
          float dv = sbuf[(l * 4 + j) * 64 + lane];
          acc[i] += ((sg >> l) & 1) ? -(double)dv : (double)dv;
        }
      }
    }
  }
  __syncthreads();   // protect sbuf reuse in epilogue

  // ---- epilogue: relu + dmat = c @ fb1^T (sbuf reused: fbt + crow) ----
#pragma unroll
  for (int i2 = 0; i2 < 8; ++i2) {
    int idx = i2 * 512 + t;                      // idx = d*64+k
    sbuf[(idx & 63) * 64 + (idx >> 6)] = fb1[idx];
  }
  float* crow = sbuf + 4096 + w * 64;
  __syncthreads();
  for (int i = 0; i < 4; ++i) {
    float cv = fmaxf((float)acc[i] + cbias[lane], 0.f);
    crow[lane] = cv;
    __syncthreads();
    double da = 0.0;
#pragma unroll
    for (int k = 0; k < 64; ++k)
      da = fma((double)crow[k], (double)sbuf[k * 64 + lane], da);
    dmat[(size_t)(c0 + w * 4 + i) * 64 + lane] = (float)da;
    __syncthreads();
  }
}

// pass 2: decode masks -> LDS clause list, then 8-deep MLP gather.
// Each (var,seg) owned by one wave -> PLAIN stores into nvd4[seg][var][64]
// (no zero-init, no atomics, deterministic).
__global__ __launch_bounds__(256, 8) void k_gather4(const u64* __restrict__ vbs,
                                                    const float* __restrict__ dmat,
                                                    double* __restrict__ nvd4) {
  __shared__ __align__(16) unsigned short list[4][LCAP];
  int w = __builtin_amdgcn_readfirstlane(threadIdx.x >> 6);
  int lane = threadIdx.x & 63;
  int seg = blockIdx.x >> 11;              // 0..GSEG-1 (changes slowest)
  int v = (blockIdx.x & 2047) * 4 + w;
  int cc0 = seg * (512 / GSEG);
  const u64* P = vbs + ((size_t)v * 512 + cc0) * 2;
  u64 a0 = P[lane * 4 + 0], a1 = P[lane * 4 + 1];
  u64 b0 = P[lane * 4 + 2], b1 = P[lane * 4 + 3];
  u64 m0 = (a0 & 0xffffffffULL) | (a1 << 32);
  u64 s0 = (a0 >> 32) | (a1 & 0xffffffff00000000ULL);
  u64 m1 = (b0 & 0xffffffffULL) | (b1 << 32);
  u64 s1 = (b0 >> 32) | (b1 & 0xffffffff00000000ULL);
  int cnt = __popcll(m0) + __popcll(m1);
  int pre = cnt;
#pragma unroll
  for (int d = 1; d < 64; d <<= 1) {
    int o = __shfl_up(pre, d, 64);
    if (lane >= d) pre += o;
  }
  int tot = __shfl(pre, 63, 64);
  int base = pre - cnt;
#pragma unroll
  for (int half = 0; half < 2; ++half) {
    u64 m = half ? m1 : m0;
    u64 s = half ? s1 : s0;
    int cbase = (cc0 + 2 * lane + half) * 64;
    while (m) {
      int b = __builtin_ctzll(m);
      m &= m - 1;
      if (base < LCAP)
        list[w][base] = (unsigned short)((cbase + b) | (((s >> b) & 1) << 15));
      ++base;
    }
  }
  __syncthreads();
  if (tot > LCAP) tot = LCAP;
  const u64* lp = (const u64*)&list[w][0];
  double acc = 0.0;
  int k = 0;
  for (; k + 8 <= tot; k += 8) {
    u64 L0 = lp[k >> 2], L1 = lp[(k >> 2) + 1];
    unsigned e[8];
#pragma unroll
    for (int q = 0; q < 4; ++q) {
      e[q] = (unsigned)(L0 >> (16 * q)) & 0xffffu;
      e[4 + q] = (unsigned)(L1 >> (16 * q)) & 0xffffu;
    }
    float dv[8];
#pragma unroll
    for (int q = 0; q < 8; ++q)
      dv[q] = dmat[(size_t)(e[q] & 0x7fffu) * 64 + lane];
#pragma unroll
    for (int q = 0; q < 8; ++q)
      acc += (e[q] & 0x8000u) ? -(double)dv[q] : (double)dv[q];
  }
  for (; k < tot; ++k) {
    unsigned e = list[w][k];
    float dv = dmat[(size_t)(e & 0x7fffu) * 64 + lane];
    acc += (e & 0x8000u) ? -(double)dv : (double)dv;
  }
  nvd4[((size_t)seg * NVAR + v) * 64 + lane] = acc;
}

// ======================= FALLBACK PATH (ws too small) =======================
__global__ __launch_bounds__(256) void k_pass1_basic(
    const float* __restrict__ pos, const float* __restrict__ neg,
    const float* __restrict__ bmat, const float* __restrict__ fb1,
    const float* __restrict__ cbias, float* __restrict__ dmat) {
  __shared__ float fbt[64 * 64];
  __shared__ float crow[4][64];
  int t = threadIdx.x;
#pragma unroll
  for (int i = 0; i < 16; ++i) {
    int idx = i * 256 + t;
    fbt[(idx & 63) * 64 + (idx >> 6)] = fb1[idx];
  }
  __syncthreads();
  int w = t >> 6, lane = t & 63;
  int c = blockIdx.x * 4 + w;
  const float4* prow = (const float4*)(pos + (size_t)c * NVAR);
  const float4* nrow = (const float4*)(neg + (size_t)c * NVAR);
  double acc = 0.0;
  for (int g = 0; g < 32; ++g) {
    float4 p = prow[g * 64 + lane];
    float4 q = nrow[g * 64 + lane];
    float sc[4];
    sc[0] = p.x - q.x; sc[1] = p.y - q.y; sc[2] = p.z - q.z; sc[3] = p.w - q.w;
#pragma unroll
    for (int j = 0; j < 4; ++j) {
      float s = sc[j];
      u64 m = __ballot(s != 0.f);
      u64 sg = __ballot(s < 0.f);
      while (m) {
        int l = __builtin_ctzll(m);
        m &= m - 1;
        float dv = bmat[(size_t)((g << 8) + (l << 2) + j) * 64 + lane];
        acc += ((sg >> l) & 1) ? -(double)dv : (double)dv;
      }
    }
  }
  float cv = fmaxf((float)acc + cbias[lane], 0.f);
  crow[w][lane] = cv;
  __syncthreads();
  double da = 0.0;
#pragma unroll
  for (int k = 0; k < 64; ++k)
    da = fma((double)crow[w][k], (double)fbt[k * 64 + lane], da);
  dmat[(size_t)c * 64 + lane] = (float)da;
}

__global__ __launch_bounds__(256) void k_pass2_dense(
    const float* __restrict__ pos, const float* __restrict__ neg,
    const float* __restrict__ dmat, double* __restrict__ nvd4) {
  __shared__ float acc[64 * 64];
  int t = threadIdx.x;
#pragma unroll
  for (int i = 0; i < 16; ++i) acc[i * 256 + t] = 0.f;
  __syncthreads();
  int w = t >> 6, lane = t & 63;
  int s = blockIdx.x / CSEG, seg = blockIdx.x % CSEG;
  int c0 = seg * (NCLS / CSEG);
  for (int c = c0 + w; c < c0 + NCLS / CSEG; c += 4) {
    float p = pos[(size_t)c * NVAR + (s << 6) + lane];
    float q = neg[(size_t)c * NVAR + (s << 6) + lane];
    float sv = p - q;
    u64 m = __ballot(sv != 0.f);
    if (!m) continue;
    float dv = dmat[(size_t)c * 64 + lane];
    while (m) {
      int l = __builtin_ctzll(m);
      m &= m - 1;
      float sl = lane_bc(sv, l);
      atomicAdd(&acc[(l << 6) + lane], sl * dv);
    }
  }
  __syncthreads();
  size_t obase = (size_t)s * 4096;
#pragma unroll
  for (int i = 0; i < 16; ++i) {
    int idx = i * 256 + t;
    atomicAdd(&nvd4[obase + idx], (double)acc[idx]);   // seg 0 buffer
  }
}

// ------- fused tail: ground-combiner + full GRU (sums 4 nvd segments) -------
__global__ __launch_bounds__(256, 1) void k_tailfused(
    const double* __restrict__ nvd4, const float* __restrict__ vb,
    const float* __restrict__ ground, const float* __restrict__ Wg,
    const float* __restrict__ bg,
    const float* __restrict__ Wz, const float* __restrict__ Uz,
    const float* __restrict__ bz,
    const float* __restrict__ Wr, const float* __restrict__ Ur,
    const float* __restrict__ br,
    const float* __restrict__ Wh, const float* __restrict__ Uh,
    const float* __restrict__ bh,
    const float* __restrict__ prev, float* __restrict__ out) {
  __shared__ float wg[72 * 65];
  __shared__ float wz[64 * 65], uz[64 * 65], wr[64 * 65], ur[64 * 65],
      wh[64 * 65], uh[64 * 65];
  __shared__ float xrow[4][72], yrow[4][64], prow[4][64], rprow[4][64];
  int t = threadIdx.x;
#pragma unroll
  for (int i = 0; i < 18; ++i) {
    int idx = i * 256 + t;
    wg[(idx % 72) * 65 + (idx / 72)] = Wg[idx];
  }
#pragma unroll
  for (int i = 0; i < 16; ++i) {
    int idx = i * 256 + t;
    int a = (idx & 63) * 65 + (idx >> 6);
    wz[a] = Wz[idx]; uz[a] = Uz[idx]; wr[a] = Wr[idx];
    ur[a] = Ur[idx]; wh[a] = Wh[idx]; uh[a] = Uh[idx];
  }
  __syncthreads();
  int w = t >> 6, lane = t & 63;
  const size_t SS = (size_t)NVAR * 64;   // segment stride
  for (int rr = 0; rr < 8; ++rr) {
    int row = blockIdx.x * 32 + w * 8 + rr;
    size_t ix = (size_t)row * 64 + lane;
    float pv = prev[ix];
    double nv = (nvd4[ix] + nvd4[SS + ix]) + (nvd4[2 * SS + ix] + nvd4[3 * SS + ix]);
    float ve = fmaxf((float)nv + vb[lane], 0.f);
    xrow[w][8 + lane] = ve;
    if (lane < 8) xrow[w][lane] = ground[row * 8 + lane];
    prow[w][lane] = pv;
    double a = 0.0;
#pragma unroll
    for (int k = 0; k < 72; ++k)
      a = fma((double)xrow[w][k], (double)wg[k * 65 + lane], a);
    float ve2 = tanhf((float)a + bg[lane]);
    yrow[w][lane] = ve2;
    float az = bz[lane], ar = br[lane];
#pragma unroll
    for (int k = 0; k < 64; ++k) {
      float y = yrow[w][k], p = prow[w][k];
      az = fmaf(y, wz[k * 65 + lane], az);
      az = fmaf(p, uz[k * 65 + lane], az);
      ar = fmaf(y, wr[k * 65 + lane], ar);
      ar = fmaf(p, ur[k * 65 + lane], ar);
    }
    float r = 1.f / (1.f + expf(-ar));
    rprow[w][lane] = r * pv;
    float ah = bh[lane];
#pragma unroll
    for (int k = 0; k < 64; ++k) {
      ah = fmaf(yrow[w][k], wh[k * 65 + lane], ah);
      ah = fmaf(rprow[w][k], uh[k * 65 + lane], ah);
    }
    float z = 1.f / (1.f + expf(-az));
    float hh = tanhf(ah);
    out[ix] = (1.f - z) * pv + z * hh;
  }
}

extern "C" void kernel_launch(void* const* d_in, const int* in_sizes, int n_in,
                              void* d_out, int out_size, void* d_ws, size_t ws_size,
                              hipStream_t stream) {
  const float* variables = (const float*)d_in[0];
  const float* ground    = (const float*)d_in[1];
  const float* cpos      = (const float*)d_in[2];
  const float* cneg      = (const float*)d_in[3];
  const float* fb        = (const float*)d_in[6];
  const float* vb        = (const float*)d_in[7];
  const float* cb        = (const float*)d_in[8];
  const float* Wg        = (const float*)d_in[9];
  const float* bg        = (const float*)d_in[10];
  const float* Wz        = (const float*)d_in[11];
  const float* Uz        = (const float*)d_in[12];
  const float* bz        = (const float*)d_in[13];
  const float* Wr        = (const float*)d_in[14];
  const float* Ur        = (const float*)d_in[15];
  const float* br        = (const float*)d_in[16];
  const float* Wh        = (const float*)d_in[17];
  const float* Uh        = (const float*)d_in[18];
  const float* bh        = (const float*)d_in[19];
  float* out = (float*)d_out;
  char* ws = (char*)d_ws;
  const size_t MB = (size_t)1 << 20;

  float* vfwd   = (float*)(ws + 0);        // 2 MB
  float* dmat   = (float*)(ws + 2 * MB);   // 8 MB
  double* nvd4  = (double*)(ws + 10 * MB); // 16 MB: [GSEG][var][64] f64
  u64* vbs      = (u64*)(ws + 26 * MB);    // 64 MB: [var][512][2]
  bool fast = ws_size >= 96 * MB;

  k_varsfwd<<<512, 256, 0, stream>>>(variables, fb, vfwd);
  if (fast) {
    k_pass1v7<<<1024, 512, 0, stream>>>(cpos, cneg, vfwd, fb + 4096, cb, dmat,
                                        vbs);
    k_gather4<<<2048 * GSEG, 256, 0, stream>>>(vbs, dmat, nvd4);
  } else {
    (void)hipMemsetAsync(nvd4, 0, (size_t)GSEG * NVAR * 64 * sizeof(double),
                         stream);
    k_pass1_basic<<<8192, 256, 0, stream>>>(cpos, cneg, vfwd, fb + 4096, cb, dmat);
    k_pass2_dense<<<128 * CSEG, 256, 0, stream>>>(cpos, cneg, dmat, nvd4);
  }
  k_tailfused<<<256, 256, 0, stream>>>(nvd4, vb, ground, Wg, bg, Wz, Uz, bz,
                                       Wr, Ur, br, Wh, Uh, bh, variables, out);
}